// Round 10
// baseline (184.323 us; speedup 1.0000x reference)
//
#include <hip/hip_runtime.h>
#include <math.h>

#define D 64
#define MAXM 20
#define CAP 32            // max groups per user (deg ~ Poisson(2))
#define CAPS 64           // max samples per group (~Poisson(4.1))
#define WPB 8             // waves (groups) per block -> 250 blocks
#define TPB 512
#define HSZ 512           // LDS hash size (pow2), load factor ~0.31
#define NBRW (MAXM * CAP + 8)  // flat neighbor-list stride per group

#define XOR_COMBINE4(v)                                        \
  do {                                                         \
    v.x += __shfl_xor(v.x, 16); v.x += __shfl_xor(v.x, 32);    \
    v.y += __shfl_xor(v.y, 16); v.y += __shfl_xor(v.y, 32);    \
    v.z += __shfl_xor(v.z, 16); v.z += __shfl_xor(v.z, 32);    \
    v.w += __shfl_xor(v.w, 16); v.w += __shfl_xor(v.w, 32);    \
  } while (0)

// Node 1: per block (8 groups) — masked-mean emb0, dedup, and LOCAL discovery
// of each member's group-list by scanning membership against an LDS hash
// (no global atomics, no pre-zeroed buffers -> no memset node). Also computes
// nm (= sum_uniq (deg-1)*U[u]) and the per-group sample index by scanning
// groups[]. Writes: emb0, nm, hdr(total,ucnt), flat nbr lists, scnt, sidx.
__global__ __launch_bounds__(TPB) void init_kernel(
    const int* __restrict__ membership, const float* __restrict__ member_mask,
    const float* __restrict__ user_emb, const int* __restrict__ groups,
    float* __restrict__ emb0, float* __restrict__ nm, int* __restrict__ hdr,
    int* __restrict__ nbrflat, int* __restrict__ scnt, int* __restrict__ sidx,
    int G, int B) {
  const int w    = threadIdx.x >> 6;
  const int lane = threadIdx.x & 63;
  const int g0   = blockIdx.x * WPB + w;
  const int g    = (g0 < G) ? g0 : G - 1;
  const int sub  = lane >> 4, q = lane & 15;

  __shared__ int   mem_s[WPB][MAXM];
  __shared__ float wgt_s[WPB][MAXM];
  __shared__ int   hkey[HSZ];           // user id or -1
  __shared__ int   hval[HSZ];           // entry idx = w*MAXM+lane
  __shared__ int   lcnt[WPB * MAXM];    // true deg per entry
  __shared__ int   lists[WPB * MAXM][CAP];
  __shared__ int   scl[WPB];
  __shared__ int   slist[WPB][CAPS];
  int*   mem = mem_s[w];
  float* wgt = wgt_s[w];

  // ---- load own rows + zero LDS structures ----
  if (g0 < G && lane < MAXM) {
    mem[lane] = membership[g0 * MAXM + lane];
    wgt[lane] = expf(member_mask[g0 * MAXM + lane]);
  }
  for (int i = threadIdx.x; i < HSZ; i += TPB) hkey[i] = -1;
  for (int i = threadIdx.x; i < WPB * MAXM; i += TPB) lcnt[i] = 0;
  if (threadIdx.x < WPB) scl[threadIdx.x] = 0;
  __syncthreads();

  // ---- phase A: masked-mean emb0 (float4 4-row gathers) + dedup + insert ---
  unsigned int um = 0u;
  if (g0 < G) {
    float wsum = 0.f;
#pragma unroll
    for (int m = 0; m < MAXM; ++m) wsum += wgt[m];
    float4 acc = make_float4(0.f, 0.f, 0.f, 0.f);
#pragma unroll
    for (int it = 0; it < MAXM / 4; ++it) {
      const int m = it * 4 + sub;
      const float c = wgt[m];
      const float4 v = *(const float4*)(user_emb + (long)mem[m] * D + q * 4);
      acc.x += c * v.x; acc.y += c * v.y; acc.z += c * v.z; acc.w += c * v.w;
    }
    XOR_COMBINE4(acc);
    if (lane < 16) {
      const float iw = 1.f / wsum;
      ((float4*)(emb0 + (long)g0 * D))[q] =
          make_float4(acc.x * iw, acc.y * iw, acc.z * iw, acc.w * iw);
    }
    bool uniq = false;
    if (lane < MAXM) {
      const int u = mem[lane];
      uniq = true;
      for (int m = 0; m < lane; ++m)
        if (mem[m] == u) uniq = false;
    }
    um = (unsigned int)__ballot(uniq);
    if (uniq) {  // insert (dup keys across rows allowed; resolved by probing)
      const int u = mem[lane];
      unsigned h = ((unsigned)u * 2654435761u) & (HSZ - 1);
      for (;;) {
        const int old = atomicCAS(&hkey[h], -1, u);
        if (old == -1) { hval[h] = w * MAXM + lane; break; }
        h = (h + 1) & (HSZ - 1);
      }
    }
  }
  __syncthreads();  // inserts complete before scan

  // ---- phase B: scan ALL membership slots; append matches to entry lists ---
  const int TOT = G * MAXM;
  for (int e = threadIdx.x; e < TOT; e += TPB) {
    const int u = membership[e];
    unsigned h = ((unsigned)u * 2654435761u) & (HSZ - 1);
    int key = hkey[h];
    if (key == -1) continue;
    int first = -1;  // lazily computed: is e the first occurrence of u in its row?
    do {
      if (key == u) {
        if (first < 0) {
          first = 1;
          const int r0 = (e / MAXM) * MAXM;
          for (int mm = r0; mm < e; ++mm)
            if (membership[mm] == u) { first = 0; break; }
        }
        if (first) {
          const int eidx = hval[h];
          const int pos = atomicAdd(&lcnt[eidx], 1);
          if (pos < CAP) lists[eidx][pos] = e / MAXM;
        }
      }
      h = (h + 1) & (HSZ - 1);
      key = hkey[h];
    } while (key != -1);
  }
  // sample index: scan groups[]; append to own-group LDS lists
  const int base_g = blockIdx.x * WPB;
  for (int s = threadIdx.x; s < B; s += TPB) {
    const unsigned rel = (unsigned)(groups[s] - base_g);
    if (rel < WPB) {
      const int pos = atomicAdd(&scl[rel], 1);
      if (pos < CAPS) slist[rel][pos] = s;
    }
  }
  __syncthreads();

  // ---- phase C: assemble per-group flat neighbor list + nm + hdr + sidx ----
  if (g0 < G) {
    int deg_t = 0, dc = 0;
    const bool uq = (lane < MAXM) && ((um >> lane) & 1u);
    if (uq) {
      deg_t = lcnt[w * MAXM + lane];
      dc = deg_t < CAP ? deg_t : CAP;
    }
    const float coef = uq ? (float)(deg_t - 1) : 0.f;
    wgt[lane < MAXM ? lane : 0] = (lane < MAXM) ? coef : wgt[0];  // reuse wgt as coef
    int incl = dc;
#pragma unroll
    for (int off = 1; off < 64; off <<= 1) {
      const int v = __shfl_up(incl, off);
      if (lane >= off) incl += v;
    }
    const int total = __shfl(incl, 63);
    const int base = incl - dc;
    for (int i = 0; i < dc; ++i)
      nbrflat[(long)g0 * NBRW + base + i] = lists[w * MAXM + lane][i];
    // nm = sum_uniq (deg-1) * U[u]
    float4 nm4 = make_float4(0.f, 0.f, 0.f, 0.f);
#pragma unroll
    for (int it = 0; it < MAXM / 4; ++it) {
      const int m = it * 4 + sub;
      const float c = wgt[m];
      const float4 v = *(const float4*)(user_emb + (long)mem[m] * D + q * 4);
      nm4.x += c * v.x; nm4.y += c * v.y; nm4.z += c * v.z; nm4.w += c * v.w;
    }
    XOR_COMBINE4(nm4);
    if (lane < 16) ((float4*)(nm + (long)g0 * D))[q] = nm4;
    if (lane == 0) {
      hdr[2 * g0]     = total;
      hdr[2 * g0 + 1] = __popc(um);
      scnt[g0] = scl[w] < CAPS ? scl[w] : CAPS;
    }
    const int ns = scl[w] < CAPS ? scl[w] : CAPS;
    for (int i = lane; i < ns; i += 64) sidx[g0 * CAPS + i] = slist[w][i];
  }
}

// Shared body: updated, l2-normalized embedding of group g using the
// precomputed flat neighbor list. All LDS wave-private -> no block barriers.
__device__ __forceinline__ float upd_core(
    const int* __restrict__ hdr, const int* __restrict__ nbrflat,
    const float* __restrict__ nm, const float* __restrict__ Wk,
    const float* __restrict__ bk, int k, const float* __restrict__ cur,
    int g, int lane, float* e_sh, float* ms_sh, int* nbr) {
  const int sub = lane >> 4, q = lane & 15;
  const int total = hdr[2 * g];
  const int ucnt  = hdr[2 * g + 1];
  const float ein = cur[(long)g * D + lane];
  e_sh[lane] = ein;
  for (int i = lane; i < total; i += 64) nbr[i] = nbrflat[(long)g * NBRW + i];
  const int padc = (8 - (total & 7)) & 7;
  if (lane < padc) nbr[total + lane] = g;   // pad rows folded into alpha

  const int T8 = total + padc;
  float4 a0 = make_float4(0.f, 0.f, 0.f, 0.f);
  float4 a1 = make_float4(0.f, 0.f, 0.f, 0.f);
  for (int i = 0; i < T8; i += 8) {
    const int r0 = nbr[i + sub];
    const int r1 = nbr[i + 4 + sub];
    const float4 v0 = *(const float4*)(cur + (long)r0 * D + q * 4);
    const float4 v1 = *(const float4*)(cur + (long)r1 * D + q * 4);
    a0.x += v0.x; a0.y += v0.y; a0.z += v0.z; a0.w += v0.w;
    a1.x += v1.x; a1.y += v1.y; a1.z += v1.z; a1.w += v1.w;
  }
  float4 ng4 = make_float4(a0.x + a1.x, a0.y + a1.y, a0.z + a1.z, a0.w + a1.w);
  XOR_COMBINE4(ng4);

  if (lane < 16) {
    const float4 nmv4 = ((const float4*)(nm + (long)g * D))[q];
    const float alpha = (float)ucnt + (float)padc;
    const float4 e4 = ((const float4*)e_sh)[q];
    float4 ms4;
    ms4.x = ng4.x + nmv4.x - alpha * e4.x;
    ms4.y = ng4.y + nmv4.y - alpha * e4.y;
    ms4.z = ng4.z + nmv4.z - alpha * e4.z;
    ms4.w = ng4.w + nmv4.w - alpha * e4.w;
    ((float4*)ms_sh)[q] = ms4;
  }

  const float4* W4 = (const float4*)(Wk + ((long)k * D + lane) * (2 * D));
  const float4* e4p = (const float4*)e_sh;
  const float4* m4p = (const float4*)ms_sh;
  float o = bk[k * D + lane];
#pragma unroll
  for (int j = 0; j < 16; ++j) {
    const float4 a = e4p[j], wv = W4[j];
    o += a.x * wv.x + a.y * wv.y + a.z * wv.z + a.w * wv.w;
  }
#pragma unroll
  for (int j = 0; j < 16; ++j) {
    const float4 a = m4p[j], wv = W4[16 + j];
    o += a.x * wv.x + a.y * wv.y + a.z * wv.z + a.w * wv.w;
  }
  float ss = o * o;
#pragma unroll
  for (int sh = 32; sh; sh >>= 1) ss += __shfl_xor(ss, sh);
  return o * (1.f / fmaxf(sqrtf(ss), 1e-12f));
}

// Node 2 (middle iterations): write updated embedding.
__global__ __launch_bounds__(TPB) void upd_kernel(
    const int* __restrict__ hdr, const int* __restrict__ nbrflat,
    const float* __restrict__ nm, const float* __restrict__ Wk,
    const float* __restrict__ bk, int k, const float* __restrict__ cur,
    float* __restrict__ nxt, int G) {
  const int w = threadIdx.x >> 6, lane = threadIdx.x & 63;
  const int g0 = blockIdx.x * WPB + w;
  const int g = g0 < G ? g0 : G - 1;
  __shared__ float e_s[WPB][D], ms_s[WPB][D];
  __shared__ int   nbr_s[WPB][NBRW];
  const float o = upd_core(hdr, nbrflat, nm, Wk, bk, k, cur, g, lane,
                           e_s[w], ms_s[w], nbr_s[w]);
  if (g0 < G) nxt[(long)g0 * D + lane] = o;
}

// Node 3: last iteration fused with the prediction head (block-pooled samples).
__global__ __launch_bounds__(TPB) void upd_head_kernel(
    const int* __restrict__ hdr, const int* __restrict__ nbrflat,
    const float* __restrict__ nm, const float* __restrict__ Wk,
    const float* __restrict__ bk, int k, const float* __restrict__ cur,
    const int* __restrict__ scnt, const int* __restrict__ sidx,
    const int* __restrict__ items, const float* __restrict__ item_emb,
    const float* __restrict__ p1w, const float* __restrict__ p1b,
    const float* __restrict__ p2w, const float* __restrict__ p2b,
    float* __restrict__ out, int G) {
  const int w = threadIdx.x >> 6, lane = threadIdx.x & 63;
  const int g0 = blockIdx.x * WPB + w;
  const int g = g0 < G ? g0 : G - 1;
  __shared__ float e_s[WPB][D], ms_s[WPB][D];
  __shared__ int   nbr_s[WPB][NBRW];
  const float o = upd_core(hdr, nbrflat, nm, Wk, bk, k, cur, g, lane,
                           e_s[w], ms_s[w], nbr_s[w]);

  __shared__ float o_sh[WPB][D];
  __shared__ int   slist[WPB * CAPS];
  __shared__ unsigned char sgw[WPB * CAPS];
  __shared__ int   soff[WPB + 1];
  __shared__ int   scnt_sh[WPB];
  o_sh[w][lane] = o;
  if (lane == 0) scnt_sh[w] = (g0 < G) ? min(scnt[g0], CAPS) : 0;
  __syncthreads();
  if (threadIdx.x == 0) {
    soff[0] = 0;
    for (int i = 0; i < WPB; ++i) soff[i + 1] = soff[i] + scnt_sh[i];
  }
  __syncthreads();
  const int my = scnt_sh[w];
  for (int i = lane; i < my; i += 64) {
    slist[soff[w] + i] = sidx[g0 * CAPS + i];
    sgw[soff[w] + i] = (unsigned char)w;
  }
  __syncthreads();
  const int T = soff[WPB];
  if (T == 0) return;
  float p1r[16], p1br[16], p2wr[16];
#pragma unroll
  for (int j = 0; j < 16; ++j) {
    p1r[j]  = p1w[j * D + lane];
    p1br[j] = p1b[j];
    p2wr[j] = p2w[j];
  }
  const float p2b0 = p2b[0];
  for (int e = w; e < T; e += WPB) {
    const int s = slist[e];
    const int gw2 = sgw[e];
    const float x = o_sh[gw2][lane] * item_emb[(long)items[s] * D + lane];
    float pv[16];
#pragma unroll
    for (int j = 0; j < 16; ++j) pv[j] = x * p1r[j];
#pragma unroll
    for (int off = 32; off; off >>= 1) {
#pragma unroll
      for (int j = 0; j < 16; ++j) pv[j] += __shfl_xor(pv[j], off);
    }
    float acc2 = p2b0;
#pragma unroll
    for (int j = 0; j < 16; ++j)
      acc2 += fmaxf(pv[j] + p1br[j], 0.f) * p2wr[j];
    if (lane == 0) out[s] = 1.f / (1.f + expf(-acc2));
  }
}

extern "C" void kernel_launch(void* const* d_in, const int* in_sizes, int n_in,
                              void* d_out, int out_size, void* d_ws, size_t ws_size,
                              hipStream_t stream) {
  const int*   groups      = (const int*)d_in[0];
  const int*   items       = (const int*)d_in[1];
  const int*   membership  = (const int*)d_in[2];
  const float* member_mask = (const float*)d_in[3];
  // d_in[4] hyper_graph: not needed (binary incidence == membership lists)
  const float* user_emb    = (const float*)d_in[5];
  const float* item_emb    = (const float*)d_in[6];
  const float* Wk          = (const float*)d_in[7];
  const float* bk          = (const float*)d_in[8];
  const float* p1w         = (const float*)d_in[9];
  const float* p1b         = (const float*)d_in[10];
  const float* p2w         = (const float*)d_in[11];
  const float* p2b         = (const float*)d_in[12];
  float* out = (float*)d_out;

  const int B  = in_sizes[0];
  const int G  = in_sizes[2] / MAXM;
  const int K  = in_sizes[7] / (D * 2 * D);

  char* ws = (char*)d_ws;
  float* emb_a   = (float*)ws; ws += (size_t)G * D * 4;
  float* emb_b   = (float*)ws; ws += (size_t)G * D * 4;
  float* nm      = (float*)ws; ws += (size_t)G * D * 4;
  int*   hdr     = (int*)ws;   ws += (size_t)G * 2 * 4;
  int*   nbrflat = (int*)ws;   ws += (size_t)G * NBRW * 4;
  int*   scnt    = (int*)ws;   ws += (size_t)G * 4;
  int*   sidx    = (int*)ws;   ws += (size_t)G * CAPS * 4;

  const int nblk = (G + WPB - 1) / WPB;   // 250 blocks

  init_kernel<<<nblk, TPB, 0, stream>>>(membership, member_mask, user_emb,
                                        groups, emb_a, nm, hdr, nbrflat,
                                        scnt, sidx, G, B);

  float* cur = emb_a;
  float* nxt = emb_b;
  for (int k = 0; k < K - 1; ++k) {
    upd_kernel<<<nblk, TPB, 0, stream>>>(hdr, nbrflat, nm, Wk, bk, k,
                                         cur, nxt, G);
    float* tmp = cur; cur = nxt; nxt = tmp;
  }
  upd_head_kernel<<<nblk, TPB, 0, stream>>>(
      hdr, nbrflat, nm, Wk, bk, K - 1, cur, scnt, sidx, items, item_emb,
      p1w, p1b, p2w, p2b, out, G);
}

// Round 11
// 57.127 us; speedup vs baseline: 3.2266x; 3.2266x over previous
//
#include <hip/hip_runtime.h>
#include <math.h>

#define D 64
#define MAXM 20
#define CAP 32    // max groups per user (deg ~ Poisson(2); P(>32) ~ 1e-27)
#define CAPS 64   // max samples per group (count ~ Poisson(4.1); P(>64) ~ 0)
#define WPB 8     // waves (groups) per block -> 250 blocks, 1 per CU
#define TPB 512

#define XOR_COMBINE4(v)                                        \
  do {                                                         \
    v.x += __shfl_xor(v.x, 16); v.x += __shfl_xor(v.x, 32);    \
    v.y += __shfl_xor(v.y, 16); v.y += __shfl_xor(v.y, 32);    \
    v.z += __shfl_xor(v.z, 16); v.z += __shfl_xor(v.z, 32);    \
    v.w += __shfl_xor(v.w, 16); v.w += __shfl_xor(v.w, 32);    \
  } while (0)

// One wave per group: masked-mean emb0 (float4 4-row gathers), dedup bitmask,
// deg/inv build. Epilogue: group->samples index (scnt/sidx).
// NOTE: mem/wgt are wave-private LDS; no cross-wave barrier needed (same-wave
// LDS RAW is ordered by compiler-inserted s_waitcnt lgkmcnt).
__global__ __launch_bounds__(TPB) void init_kernel(
    const int* __restrict__ membership, const float* __restrict__ member_mask,
    const float* __restrict__ user_emb, const int* __restrict__ groups,
    float* __restrict__ emb0, unsigned int* __restrict__ ufm,
    int* __restrict__ deg, int* __restrict__ inv,
    int* __restrict__ scnt, int* __restrict__ sidx, int G, int B) {
  const int w    = threadIdx.x >> 6;
  const int lane = threadIdx.x & 63;
  const int g    = blockIdx.x * WPB + w;
  const int sub  = lane >> 4, q = lane & 15;
  __shared__ int   mem_s[WPB][MAXM];
  __shared__ float wgt_s[WPB][MAXM];
  int*   mem = mem_s[w];
  float* wgt = wgt_s[w];
  if (g < G) {
    if (lane < MAXM) {
      mem[lane] = membership[g * MAXM + lane];
      wgt[lane] = expf(member_mask[g * MAXM + lane]);
    }
    float wsum = 0.f;
#pragma unroll
    for (int m = 0; m < MAXM; ++m) wsum += wgt[m];
    float4 acc = make_float4(0.f, 0.f, 0.f, 0.f);
#pragma unroll
    for (int it = 0; it < MAXM / 4; ++it) {   // 4 rows per instruction
      const int m = it * 4 + sub;
      const float c = wgt[m];
      const float4 v = *(const float4*)(user_emb + (long)mem[m] * D + q * 4);
      acc.x += c * v.x; acc.y += c * v.y; acc.z += c * v.z; acc.w += c * v.w;
    }
    XOR_COMBINE4(acc);
    if (lane < 16) {
      const float iw = 1.f / wsum;
      float4 r = make_float4(acc.x * iw, acc.y * iw, acc.z * iw, acc.w * iw);
      ((float4*)(emb0 + (long)g * D))[q] = r;
    }
    bool uniq = false;
    if (lane < MAXM) {
      const int u = mem[lane];
      uniq = true;
      for (int m = 0; m < lane; ++m)
        if (mem[m] == u) uniq = false;
    }
    const unsigned long long bal = __ballot(uniq);
    if (lane == 0) ufm[g] = (unsigned int)bal;
    if (uniq) {
      const int u = mem[lane];
      const int pos = atomicAdd(&deg[u], 1);
      if (pos < CAP) inv[(long)u * CAP + pos] = g;
    }
  }
  // group->samples index
  const int nthreads = gridDim.x * TPB;
  for (int s = blockIdx.x * TPB + threadIdx.x; s < B; s += nthreads) {
    const int gg = groups[s];
    const int pos = atomicAdd(&scnt[gg], 1);
    if (pos < CAPS) sidx[gg * CAPS + pos] = s;
  }
}

// Shared body: updated, l2-normalized embedding of group g. All LDS arrays
// are wave-private -> no block barriers. ng via inverse-index gather, 8 rows
// in flight (2x unrolled float4 4-row loads); pad rows = g, folded into the
// -(ucnt+padc)*e term. nm computed at k==0, reread after.
__device__ __forceinline__ float update_core(
    const int* __restrict__ membership, const unsigned int* __restrict__ ufm,
    const int* __restrict__ deg, const int* __restrict__ inv,
    const float* __restrict__ user_emb, float* __restrict__ nm, int compute_nm,
    const float* __restrict__ Wk, const float* __restrict__ bk, int k,
    const float* __restrict__ cur, int g, int lane,
    int* mem, float* coef, float* e_sh, float* ms_sh, int* nbr) {
  const int sub = lane >> 4, q = lane & 15;
  if (lane < MAXM) mem[lane] = membership[g * MAXM + lane];
  const unsigned int um = ufm[g];
  const float ein = cur[(long)g * D + lane];
  e_sh[lane] = ein;

  int d = 0, u = 0;
  const bool uq = (lane < MAXM) && ((um >> lane) & 1u);
  if (uq) { u = mem[lane]; d = deg[u]; }
  if (lane < MAXM) coef[lane] = uq ? (float)(d - 1) : 0.f;
  const int dc = d < CAP ? d : CAP;
  int incl = dc;
#pragma unroll
  for (int off = 1; off < 64; off <<= 1) {
    const int v = __shfl_up(incl, off);
    if (lane >= off) incl += v;
  }
  const int total = __shfl(incl, 63);
  const int base = incl - dc;
  for (int i = 0; i < dc; ++i) nbr[base + i] = inv[(long)u * CAP + i];
  const int padc = (8 - (total & 7)) & 7;
  if (lane < padc) nbr[total + lane] = g;   // pad rows: subtracted via alpha

  const int T8 = total + padc;
  float4 a0 = make_float4(0.f, 0.f, 0.f, 0.f);
  float4 a1 = make_float4(0.f, 0.f, 0.f, 0.f);
  for (int i = 0; i < T8; i += 8) {
    const int r0 = nbr[i + sub];
    const int r1 = nbr[i + 4 + sub];
    const float4 v0 = *(const float4*)(cur + (long)r0 * D + q * 4);
    const float4 v1 = *(const float4*)(cur + (long)r1 * D + q * 4);
    a0.x += v0.x; a0.y += v0.y; a0.z += v0.z; a0.w += v0.w;
    a1.x += v1.x; a1.y += v1.y; a1.z += v1.z; a1.w += v1.w;
  }
  float4 ng4 = make_float4(a0.x + a1.x, a0.y + a1.y, a0.z + a1.z, a0.w + a1.w);
  XOR_COMBINE4(ng4);

  float4 nm4 = make_float4(0.f, 0.f, 0.f, 0.f);
  if (compute_nm) {
#pragma unroll
    for (int it = 0; it < MAXM / 4; ++it) {
      const int m = it * 4 + sub;
      const float c = coef[m];
      const float4 v = *(const float4*)(user_emb + (long)mem[m] * D + q * 4);
      nm4.x += c * v.x; nm4.y += c * v.y; nm4.z += c * v.z; nm4.w += c * v.w;
    }
    XOR_COMBINE4(nm4);
    if (lane < 16) ((float4*)(nm + (long)g * D))[q] = nm4;
  }
  if (lane < 16) {
    const float4 nmv4 =
        compute_nm ? nm4 : ((const float4*)(nm + (long)g * D))[q];
    const float alpha = (float)__popc(um) + (float)padc;
    const float4 e4 = ((const float4*)e_sh)[q];
    float4 ms4;
    ms4.x = ng4.x + nmv4.x - alpha * e4.x;
    ms4.y = ng4.y + nmv4.y - alpha * e4.y;
    ms4.z = ng4.z + nmv4.z - alpha * e4.z;
    ms4.w = ng4.w + nmv4.w - alpha * e4.w;
    ((float4*)ms_sh)[q] = ms4;
  }

  const float4* W4 = (const float4*)(Wk + ((long)k * D + lane) * (2 * D));
  const float4* e4p = (const float4*)e_sh;
  const float4* m4p = (const float4*)ms_sh;
  float o = bk[k * D + lane];
#pragma unroll
  for (int j = 0; j < 16; ++j) {
    const float4 a = e4p[j], wv = W4[j];
    o += a.x * wv.x + a.y * wv.y + a.z * wv.z + a.w * wv.w;
  }
#pragma unroll
  for (int j = 0; j < 16; ++j) {
    const float4 a = m4p[j], wv = W4[16 + j];
    o += a.x * wv.x + a.y * wv.y + a.z * wv.z + a.w * wv.w;
  }
  float ss = o * o;
#pragma unroll
  for (int sh = 32; sh; sh >>= 1) ss += __shfl_xor(ss, sh);
  return o * (1.f / fmaxf(sqrtf(ss), 1e-12f));
}

// Middle iteration: writes updated embedding.
__global__ __launch_bounds__(TPB) void upd_kernel(
    const int* __restrict__ membership, const unsigned int* __restrict__ ufm,
    const int* __restrict__ deg, const int* __restrict__ inv,
    const float* __restrict__ user_emb, float* __restrict__ nm, int compute_nm,
    const float* __restrict__ Wk, const float* __restrict__ bk, int k,
    const float* __restrict__ cur, float* __restrict__ nxt, int G) {
  const int w = threadIdx.x >> 6, lane = threadIdx.x & 63;
  const int g0 = blockIdx.x * WPB + w;
  const int g = g0 < G ? g0 : G - 1;
  __shared__ int   mem_s[WPB][MAXM];
  __shared__ float coef_s[WPB][MAXM];
  __shared__ float e_s[WPB][D], ms_s[WPB][D];
  __shared__ int   nbr_s[WPB][MAXM * CAP + 8];
  const float o = update_core(membership, ufm, deg, inv, user_emb, nm,
                              compute_nm, Wk, bk, k, cur, g, lane,
                              mem_s[w], coef_s[w], e_s[w], ms_s[w], nbr_s[w]);
  if (g0 < G) nxt[(long)g0 * D + lane] = o;
}

// Last iteration fused with the prediction head; the block's waves pool
// their groups' samples to cut straggler tails.
__global__ __launch_bounds__(TPB) void upd_head_kernel(
    const int* __restrict__ membership, const unsigned int* __restrict__ ufm,
    const int* __restrict__ deg, const int* __restrict__ inv,
    const float* __restrict__ user_emb, float* __restrict__ nm, int compute_nm,
    const float* __restrict__ Wk, const float* __restrict__ bk, int k,
    const float* __restrict__ cur,
    const int* __restrict__ scnt, const int* __restrict__ sidx,
    const int* __restrict__ items, const float* __restrict__ item_emb,
    const float* __restrict__ p1w, const float* __restrict__ p1b,
    const float* __restrict__ p2w, const float* __restrict__ p2b,
    float* __restrict__ out, int G) {
  const int w = threadIdx.x >> 6, lane = threadIdx.x & 63;
  const int g0 = blockIdx.x * WPB + w;
  const int g = g0 < G ? g0 : G - 1;
  __shared__ int   mem_s[WPB][MAXM];
  __shared__ float coef_s[WPB][MAXM];
  __shared__ float e_s[WPB][D], ms_s[WPB][D];
  __shared__ int   nbr_s[WPB][MAXM * CAP + 8];
  const float o = update_core(membership, ufm, deg, inv, user_emb, nm,
                              compute_nm, Wk, bk, k, cur, g, lane,
                              mem_s[w], coef_s[w], e_s[w], ms_s[w], nbr_s[w]);

  __shared__ float o_sh[WPB][D];
  __shared__ int   slist[WPB * CAPS];
  __shared__ unsigned char sgw[WPB * CAPS];
  __shared__ int   soff[WPB + 1];
  __shared__ int   scnt_sh[WPB];
  o_sh[w][lane] = o;
  if (lane == 0) scnt_sh[w] = (g0 < G) ? min(scnt[g0], CAPS) : 0;
  __syncthreads();
  if (threadIdx.x == 0) {
    soff[0] = 0;
    for (int i = 0; i < WPB; ++i) soff[i + 1] = soff[i] + scnt_sh[i];
  }
  __syncthreads();
  const int my = scnt_sh[w];
  for (int i = lane; i < my; i += 64) {
    slist[soff[w] + i] = sidx[g0 * CAPS + i];
    sgw[soff[w] + i] = (unsigned char)w;
  }
  __syncthreads();
  const int T = soff[WPB];
  if (T == 0) return;
  float p1r[16], p1br[16], p2wr[16];
#pragma unroll
  for (int j = 0; j < 16; ++j) {
    p1r[j]  = p1w[j * D + lane];
    p1br[j] = p1b[j];
    p2wr[j] = p2w[j];
  }
  const float p2b0 = p2b[0];
  for (int e = w; e < T; e += WPB) {
    const int s = slist[e];
    const int gw2 = sgw[e];
    const float x = o_sh[gw2][lane] * item_emb[(long)items[s] * D + lane];
    float pv[16];
#pragma unroll
    for (int j = 0; j < 16; ++j) pv[j] = x * p1r[j];
#pragma unroll
    for (int off = 32; off; off >>= 1) {
#pragma unroll
      for (int j = 0; j < 16; ++j) pv[j] += __shfl_xor(pv[j], off);
    }
    float acc2 = p2b0;
#pragma unroll
    for (int j = 0; j < 16; ++j)
      acc2 += fmaxf(pv[j] + p1br[j], 0.f) * p2wr[j];
    if (lane == 0) out[s] = 1.f / (1.f + expf(-acc2));
  }
}

extern "C" void kernel_launch(void* const* d_in, const int* in_sizes, int n_in,
                              void* d_out, int out_size, void* d_ws, size_t ws_size,
                              hipStream_t stream) {
  const int*   groups      = (const int*)d_in[0];
  const int*   items       = (const int*)d_in[1];
  const int*   membership  = (const int*)d_in[2];
  const float* member_mask = (const float*)d_in[3];
  // d_in[4] hyper_graph: not needed (binary incidence == membership lists)
  const float* user_emb    = (const float*)d_in[5];
  const float* item_emb    = (const float*)d_in[6];
  const float* Wk          = (const float*)d_in[7];
  const float* bk          = (const float*)d_in[8];
  const float* p1w         = (const float*)d_in[9];
  const float* p1b         = (const float*)d_in[10];
  const float* p2w         = (const float*)d_in[11];
  const float* p2b         = (const float*)d_in[12];
  float* out = (float*)d_out;

  const int B  = in_sizes[0];
  const int G  = in_sizes[2] / MAXM;
  const int NU = in_sizes[5] / D;
  const int K  = in_sizes[7] / (D * 2 * D);

  char* ws = (char*)d_ws;
  float*        emb_a = (float*)ws;        ws += (size_t)G * D * 4;
  float*        emb_b = (float*)ws;        ws += (size_t)G * D * 4;
  float*        nm    = (float*)ws;        ws += (size_t)G * D * 4;
  int*          deg   = (int*)ws;          ws += (size_t)NU * 4;   // contiguous
  int*          scnt  = (int*)ws;          ws += (size_t)G * 4;    // with deg
  int*          inv   = (int*)ws;          ws += (size_t)NU * CAP * 4;
  int*          sidx  = (int*)ws;          ws += (size_t)G * CAPS * 4;
  unsigned int* ufm   = (unsigned int*)ws; ws += (size_t)G * 4;

  const int nblk = (G + WPB - 1) / WPB;   // 250 blocks: one per CU, uniform

  hipMemsetAsync(deg, 0, (size_t)(NU + G) * 4, stream);  // deg + scnt
  init_kernel<<<nblk, TPB, 0, stream>>>(membership, member_mask, user_emb,
                                        groups, emb_a, ufm, deg, inv,
                                        scnt, sidx, G, B);

  float* cur = emb_a;
  float* nxt = emb_b;
  for (int k = 0; k < K - 1; ++k) {
    upd_kernel<<<nblk, TPB, 0, stream>>>(membership, ufm, deg, inv, user_emb,
                                         nm, (k == 0) ? 1 : 0, Wk, bk, k,
                                         cur, nxt, G);
    float* tmp = cur; cur = nxt; nxt = tmp;
  }
  upd_head_kernel<<<nblk, TPB, 0, stream>>>(
      membership, ufm, deg, inv, user_emb, nm, (K == 1) ? 1 : 0, Wk, bk, K - 1,
      cur, scnt, sidx, items, item_emb, p1w, p1b, p2w, p2b, out, G);
}